// Round 6
// baseline (553.317 us; speedup 1.0000x reference)
//
#include <hip/hip_runtime.h>
#include <hip/hip_bf16.h>

#ifndef MIN
#define MIN(a,b) ((a)<(b)?(a):(b))
#endif

typedef _Float16 half2_t __attribute__((ext_vector_type(2)));
typedef _Float16 half4_t __attribute__((ext_vector_type(4)));
typedef _Float16 half8_t __attribute__((ext_vector_type(8)));
typedef float floatx4 __attribute__((ext_vector_type(4)));

#define BUCKET_SHIFT 6
#define BUCKET_SIZE 64

// ---------------------------------------------------------------------------
// Bucketed CSR build (counting sort by dst, 64-node buckets)
// ---------------------------------------------------------------------------

// Pass A: histogram edges into buckets (LDS-local, one global flush per block)
__global__ void hist_kernel(const int* __restrict__ dst, int E,
                            int* __restrict__ bucketCnt, int NB) {
    __shared__ int h[1024];
    int t = threadIdx.x;
    for (int i = t; i < 1024; i += 256) h[i] = 0;
    __syncthreads();
    for (int e = blockIdx.x * 256 + t; e < E; e += gridDim.x * 256)
        atomicAdd(&h[dst[e] >> BUCKET_SHIFT], 1);
    __syncthreads();
    for (int i = t; i < NB; i += 256)
        if (h[i]) atomicAdd(&bucketCnt[i], h[i]);
}

// one block, 1024 threads: exclusive scan of bucket counts (NB <= 1024)
__global__ void bucket_scan(const int* __restrict__ bucketCnt,
                            int* __restrict__ bucketBase, int* __restrict__ bucketCur,
                            int NB, int E) {
    __shared__ int sm[1024];
    int t = threadIdx.x;
    int v = (t < NB) ? bucketCnt[t] : 0;
    sm[t] = v;
    __syncthreads();
    for (int off = 1; off < 1024; off <<= 1) {
        int add = (t >= off) ? sm[t - off] : 0;
        __syncthreads();
        sm[t] += add;
        __syncthreads();
    }
    if (t < NB) {
        bucketBase[t] = sm[t] - v;
        bucketCur[t] = sm[t] - v;
    }
    if (t == 0) bucketBase[NB] = E;
}

// Pass B: scatter {src,dst} records into bucket-ordered array
__global__ void scatter_kernel(const int* __restrict__ src, const int* __restrict__ dst,
                               int E, int* __restrict__ bucketCur, uint2* __restrict__ rec) {
    int e = blockIdx.x * blockDim.x + threadIdx.x;
    if (e < E) {
        int d = dst[e];
        int pos = atomicAdd(&bucketCur[d >> BUCKET_SHIFT], 1);
        rec[pos] = make_uint2((unsigned)src[e], (unsigned)d);
    }
}

// Pass C: one block per bucket — per-node degree, local scan, rowptr/dinv/csr fill
__global__ void bucket_build(const uint2* __restrict__ rec, const int* __restrict__ bucketBase,
                             int* __restrict__ rowptr, int* __restrict__ csr_src,
                             float* __restrict__ dinv, int N, int E) {
    __shared__ int lcnt[256];   // only [0,64) used; padded for uniform scan
    __shared__ int sm[256];
    __shared__ int lcur[64];
    int b = blockIdx.x;
    int t = threadIdx.x;
    int beg = bucketBase[b], end = bucketBase[b + 1];
    lcnt[t] = 0;
    __syncthreads();
    for (int i = beg + t; i < end; i += 256)
        atomicAdd(&lcnt[rec[i].y & (BUCKET_SIZE - 1)], 1);
    __syncthreads();
    int v = lcnt[t];
    sm[t] = v;
    __syncthreads();
    for (int off = 1; off < 256; off <<= 1) {
        int add = (t >= off) ? sm[t - off] : 0;
        __syncthreads();
        sm[t] += add;
        __syncthreads();
    }
    int excl = sm[t] - v;
    if (t < BUCKET_SIZE) {
        int node = b * BUCKET_SIZE + t;
        if (node < N) {
            rowptr[node] = beg + excl;
            dinv[node] = rsqrtf((float)(v + 1));   // self loop -> deg >= 1
        }
        lcur[t] = beg + excl;
    }
    __syncthreads();
    for (int i = beg + t; i < end; i += 256) {
        uint2 r = rec[i];
        int pos = atomicAdd(&lcur[r.y & (BUCKET_SIZE - 1)], 1);
        csr_src[pos] = (int)r.x;
    }
    if (b == 0 && t == 0) rowptr[N] = E;
}

// ---------------------------------------------------------------------------
// Weight fp32 -> f16 conversion (once per call; 3 arrays in one launch)
// ---------------------------------------------------------------------------

__global__ void cvt_weights(const float* __restrict__ a, _Float16* __restrict__ oa, int na,
                            const float* __restrict__ b, _Float16* __restrict__ ob, int nb,
                            const float* __restrict__ c, _Float16* __restrict__ oc, int nc) {
    int i = blockIdx.x * blockDim.x + threadIdx.x;
    if (i < na) oa[i] = (_Float16)a[i];
    if (i < nb) ob[i] = (_Float16)b[i];
    if (i < nc) oc[i] = (_Float16)c[i];
}

// ---------------------------------------------------------------------------
// Aggregation over f16 H: X[node] = relu( di*( di*H[node] + sum dinv[s]*H[s] ) )
// 1 wave per node, 1 dword (2 f16 ch) per lane; 64-edge batches via shfl,
// 8 independent row gathers in flight. Accumulate fp32; X written f16.
// ---------------------------------------------------------------------------

__global__ void agg_kernel(const half2_t* __restrict__ Hb, const float* __restrict__ dinv,
                           const int* __restrict__ rowptr, const int* __restrict__ csr_src,
                           half2_t* __restrict__ X, int N) {
    int node = blockIdx.x * 4 + (threadIdx.x >> 6);
    int t = threadIdx.x & 63;
    if (node >= N) return;
    float di = dinv[node];
    half2_t hu = Hb[(size_t)node * 64 + t];
    float2 acc;
    acc.x = (float)hu.x * di;
    acc.y = (float)hu.y * di;
    int beg = rowptr[node];
    int end = rowptr[node + 1];

    for (int base = beg; base < end; base += 64) {
        int idx = base + t;
        bool valid = idx < end;
        int s_lane = valid ? csr_src[idx] : node;    // safe address for pads
        float w_lane = valid ? dinv[s_lane] : 0.0f;  // zero weight for pads
        int m = end - base;
        if (m > 64) m = 64;
        int mm = (m + 7) & ~7;                       // pads contribute 0
        for (int j = 0; j < mm; j += 8) {
            int s0 = __shfl(s_lane, j + 0), s1 = __shfl(s_lane, j + 1);
            int s2 = __shfl(s_lane, j + 2), s3 = __shfl(s_lane, j + 3);
            int s4 = __shfl(s_lane, j + 4), s5 = __shfl(s_lane, j + 5);
            int s6 = __shfl(s_lane, j + 6), s7 = __shfl(s_lane, j + 7);
            float w0 = __shfl(w_lane, j + 0), w1 = __shfl(w_lane, j + 1);
            float w2 = __shfl(w_lane, j + 2), w3 = __shfl(w_lane, j + 3);
            float w4 = __shfl(w_lane, j + 4), w5 = __shfl(w_lane, j + 5);
            float w6 = __shfl(w_lane, j + 6), w7 = __shfl(w_lane, j + 7);
            half2_t u0 = Hb[(size_t)s0 * 64 + t];
            half2_t u1 = Hb[(size_t)s1 * 64 + t];
            half2_t u2 = Hb[(size_t)s2 * 64 + t];
            half2_t u3 = Hb[(size_t)s3 * 64 + t];
            half2_t u4 = Hb[(size_t)s4 * 64 + t];
            half2_t u5 = Hb[(size_t)s5 * 64 + t];
            half2_t u6 = Hb[(size_t)s6 * 64 + t];
            half2_t u7 = Hb[(size_t)s7 * 64 + t];
            acc.x = fmaf((float)u0.x, w0, acc.x); acc.y = fmaf((float)u0.y, w0, acc.y);
            acc.x = fmaf((float)u1.x, w1, acc.x); acc.y = fmaf((float)u1.y, w1, acc.y);
            acc.x = fmaf((float)u2.x, w2, acc.x); acc.y = fmaf((float)u2.y, w2, acc.y);
            acc.x = fmaf((float)u3.x, w3, acc.x); acc.y = fmaf((float)u3.y, w3, acc.y);
            acc.x = fmaf((float)u4.x, w4, acc.x); acc.y = fmaf((float)u4.y, w4, acc.y);
            acc.x = fmaf((float)u5.x, w5, acc.x); acc.y = fmaf((float)u5.y, w5, acc.y);
            acc.x = fmaf((float)u6.x, w6, acc.x); acc.y = fmaf((float)u6.y, w6, acc.y);
            acc.x = fmaf((float)u7.x, w7, acc.x); acc.y = fmaf((float)u7.y, w7, acc.y);
        }
    }
    half2_t o;
    o.x = (_Float16)fmaxf(acc.x * di, 0.0f);
    o.y = (_Float16)fmaxf(acc.y * di, 0.0f);
    X[(size_t)node * 64 + t] = o;
}

// ---------------------------------------------------------------------------
// MFMA f16 GEMM, K=128 fixed, BM=64, 256 threads (4 waves, 16 rows/wave).
// C[m][n] = sum_k A[m][k] * W[n][k]  (+bias[n]) (relu) -> f16 or fp32(+=) out.
// Fragment layout (verified m89/m91/m120): A/B lane reads row=lane&15,
// k=(lane>>4)*8..+7 ; C/D col=lane&15, row=(lane>>4)*4+reg.
// ---------------------------------------------------------------------------

template <int BN, bool A_F16, bool RELU, bool BIAS, bool ACCUM, bool F16OUT>
__global__ __launch_bounds__(256)
void mfma_gemm(const void* __restrict__ Av,
               const _Float16* __restrict__ W, int ldw,
               const float* __restrict__ bias,
               void* __restrict__ Cv, int ldc, int M) {
    constexpr int NT = BN / 16;
    __shared__ __align__(16) _Float16 As[64][136];
    __shared__ __align__(16) _Float16 Ws[BN][136];

    int tid = threadIdx.x;
    int rowBase = blockIdx.x * 64;

    // ---- stage W (f16, pre-converted) ----
#pragma unroll
    for (int i = tid; i < BN * 16; i += 256) {
        int n = i >> 4, k8 = (i & 15) * 8;
        uint4 v = *(const uint4*)(W + (size_t)n * ldw + k8);
        *(uint4*)(&Ws[n][k8]) = v;
    }
    // ---- stage A ----
    if (A_F16) {
        const _Float16* A = (const _Float16*)Av;
#pragma unroll
        for (int i = tid; i < 64 * 16; i += 256) {
            int r = i >> 4, k8 = (i & 15) * 8;
            int gr = rowBase + r;
            uint4 v = make_uint4(0, 0, 0, 0);
            if (gr < M) v = *(const uint4*)(A + (size_t)gr * 128 + k8);
            *(uint4*)(&As[r][k8]) = v;
        }
    } else {
        const float* A = (const float*)Av;
#pragma unroll
        for (int i = tid; i < 64 * 32; i += 256) {
            int r = i >> 5, c4 = (i & 31) * 4;
            int gr = rowBase + r;
            half4_t h = {0, 0, 0, 0};
            if (gr < M) {
                float4 v = *(const float4*)(A + (size_t)gr * 128 + c4);
                h.x = (_Float16)v.x; h.y = (_Float16)v.y;
                h.z = (_Float16)v.z; h.w = (_Float16)v.w;
            }
            *(half4_t*)(&As[r][c4]) = h;
        }
    }
    __syncthreads();

    // ---- compute ----
    int w = tid >> 6;          // wave id: rows w*16..w*16+15
    int lane = tid & 63;
    int lrow = lane & 15;
    int kq = (lane >> 4) * 8;

    floatx4 acc[NT];
#pragma unroll
    for (int nt = 0; nt < NT; ++nt) acc[nt] = (floatx4){0.f, 0.f, 0.f, 0.f};

#pragma unroll
    for (int ks = 0; ks < 4; ++ks) {
        int kk = ks * 32 + kq;
        half8_t a = *(const half8_t*)(&As[w * 16 + lrow][kk]);
#pragma unroll
        for (int nt = 0; nt < NT; ++nt) {
            half8_t b = *(const half8_t*)(&Ws[nt * 16 + lrow][kk]);
            acc[nt] = __builtin_amdgcn_mfma_f32_16x16x32_f16(a, b, acc[nt], 0, 0, 0);
        }
    }

    // ---- epilogue ----
    int quad = lane >> 4;
#pragma unroll
    for (int nt = 0; nt < NT; ++nt) {
        int col = nt * 16 + lrow;
        float bv = BIAS ? bias[col] : 0.0f;
#pragma unroll
        for (int reg = 0; reg < 4; ++reg) {
            int gr = rowBase + w * 16 + quad * 4 + reg;
            if (gr < M) {
                float v = acc[nt][reg] + bv;
                if (RELU) v = fmaxf(v, 0.0f);
                if (F16OUT) {
                    _Float16* C = (_Float16*)Cv;
                    C[(size_t)gr * ldc + col] = (_Float16)v;
                } else {
                    float* C = (float*)Cv;
                    if (ACCUM) v += C[(size_t)gr * ldc + col];
                    C[(size_t)gr * ldc + col] = v;
                }
            }
        }
    }
}

// ---------------------------------------------------------------------------
// launch
// ---------------------------------------------------------------------------

extern "C" void kernel_launch(void* const* d_in, const int* in_sizes, int n_in,
                              void* d_out, int out_size, void* d_ws, size_t ws_size,
                              hipStream_t stream) {
    const float* x     = (const float*)d_in[0];
    const int*   ei    = (const int*)d_in[1];
    const float* W_in  = (const float*)d_in[2];
    const float* b_in  = (const float*)d_in[3];
    const float* Wc    = (const float*)d_in[4];
    const float* bc    = (const float*)d_in[5];
    const float* W_out = (const float*)d_in[6];
    const float* b_out = (const float*)d_in[7];
    float* out = (float*)d_out;

    const int HID = 128;
    const int N = in_sizes[0] / HID;   // 50000
    const int E = in_sizes[1] / 2;     // 800000
    const int L = 4;
    const int* src = ei;
    const int* dst = ei + E;
    const int NB = (N + BUCKET_SIZE - 1) >> BUCKET_SHIFT;   // 782

    char* ws = (char*)d_ws;
    size_t off = 0;
    auto carve = [&](size_t bytes) {
        void* p = ws + off;
        off += (bytes + 255) & ~(size_t)255;
        return p;
    };
    float* dinv      = (float*)carve((size_t)N * 4);
    int*   rowptr    = (int*)carve((size_t)(N + 1) * 4);
    int*   csr_src   = (int*)carve((size_t)E * 4);
    uint2* rec       = (uint2*)carve((size_t)E * 8);
    int*   bucketCnt = (int*)carve((size_t)1024 * 4);
    int*   bucketBase= (int*)carve((size_t)1025 * 4);
    int*   bucketCur = (int*)carve((size_t)1024 * 4);
    _Float16* bufA   = (_Float16*)carve((size_t)N * HID * 2);   // f16 activations
    _Float16* bufH   = (_Float16*)carve((size_t)N * HID * 2);   // f16 pre-agg
    _Float16* Wf_in  = (_Float16*)carve((size_t)HID * HID * 2);
    _Float16* Wf_c   = (_Float16*)carve((size_t)L * HID * HID * 2);
    _Float16* Wf_out = (_Float16*)carve((size_t)64 * 512 * 2);
    (void)ws_size;

    // ---- bucketed CSR + norm build ----
    hipMemsetAsync(bucketCnt, 0, (size_t)1024 * 4, stream);
    hist_kernel<<<512, 256, 0, stream>>>(dst, E, bucketCnt, NB);
    bucket_scan<<<1, 1024, 0, stream>>>(bucketCnt, bucketBase, bucketCur, NB, E);
    scatter_kernel<<<(E + 255) / 256, 256, 0, stream>>>(src, dst, E, bucketCur, rec);
    bucket_build<<<NB, 256, 0, stream>>>(rec, bucketBase, rowptr, csr_src, dinv, N, E);

    // ---- weights -> f16 ----
    cvt_weights<<<(L * HID * HID + 255) / 256, 256, 0, stream>>>(
        W_in, Wf_in, HID * HID,
        Wc, Wf_c, L * HID * HID,
        W_out, Wf_out, 64 * 512);

    int gemm_blocks = (N + 63) / 64;

    // ---- input projection: bufA = f16( relu(x @ W_in^T + b_in) ) ----
    mfma_gemm<128, false, true, true, false, true>
        <<<gemm_blocks, 256, 0, stream>>>(x, Wf_in, HID, b_in, bufA, HID, N);

    // ---- conv layers ----
    for (int l = 0; l < L; ++l) {
        // bufH = f16( bufA @ Wc[l]^T + bc[l] )
        mfma_gemm<128, true, false, true, false, true>
            <<<gemm_blocks, 256, 0, stream>>>(bufA, Wf_c + (size_t)l * HID * HID, HID,
                                              bc + (size_t)l * HID, bufH, HID, N);
        // bufA = f16( relu(aggregate(bufH)) )
        agg_kernel<<<(N + 3) / 4, 256, 0, stream>>>((const half2_t*)bufH, dinv, rowptr,
                                                    csr_src, (half2_t*)bufA, N);
        // out (+)= bufA @ W_out[:, l*128:(l+1)*128]^T  (+ b_out at l==0)
        if (l == 0) {
            mfma_gemm<64, true, false, true, false, false>
                <<<gemm_blocks, 256, 0, stream>>>(bufA, Wf_out + (size_t)l * HID, 512,
                                                  b_out, out, 64, N);
        } else {
            mfma_gemm<64, true, false, false, true, false>
                <<<gemm_blocks, 256, 0, stream>>>(bufA, Wf_out + (size_t)l * HID, 512,
                                                  nullptr, out, 64, N);
        }
    }
}

// Round 7
// 390.213 us; speedup vs baseline: 1.4180x; 1.4180x over previous
//
#include <hip/hip_runtime.h>
#include <hip/hip_bf16.h>

#ifndef MIN
#define MIN(a,b) ((a)<(b)?(a):(b))
#endif

typedef _Float16 half2_t __attribute__((ext_vector_type(2)));
typedef _Float16 half4_t __attribute__((ext_vector_type(4)));
typedef _Float16 half8_t __attribute__((ext_vector_type(8)));
typedef float floatx4 __attribute__((ext_vector_type(4)));

#define BUCKET_SHIFT 6
#define BUCKET_SIZE 64
#define SCHUNK 8192

// ---------------------------------------------------------------------------
// Bucketed CSR build (counting sort by dst, 64-node buckets)
// ---------------------------------------------------------------------------

// Pass A: histogram edges into buckets (LDS-local, fire-and-forget flush)
__global__ void hist_kernel(const int* __restrict__ dst, int E,
                            int* __restrict__ bucketCnt, int NB) {
    __shared__ int h[1024];
    int t = threadIdx.x;
    for (int i = t; i < 1024; i += 256) h[i] = 0;
    __syncthreads();
    for (int e = blockIdx.x * 256 + t; e < E; e += gridDim.x * 256)
        atomicAdd(&h[dst[e] >> BUCKET_SHIFT], 1);
    __syncthreads();
    for (int i = t; i < NB; i += 256)
        if (h[i]) atomicAdd(&bucketCnt[i], h[i]);   // no return use -> pipelined
}

// one block, 1024 threads: exclusive scan of bucket counts (NB <= 1024)
__global__ void bucket_scan(const int* __restrict__ bucketCnt,
                            int* __restrict__ bucketBase, int* __restrict__ bucketCur,
                            int NB, int E) {
    __shared__ int sm[1024];
    int t = threadIdx.x;
    int v = (t < NB) ? bucketCnt[t] : 0;
    sm[t] = v;
    __syncthreads();
    for (int off = 1; off < 1024; off <<= 1) {
        int add = (t >= off) ? sm[t - off] : 0;
        __syncthreads();
        sm[t] += add;
        __syncthreads();
    }
    if (t < NB) {
        bucketBase[t] = sm[t] - v;
        bucketCur[t] = sm[t] - v;
    }
    if (t == 0) bucketBase[NB] = E;
}

// Pass B: two-level scatter. Per 8192-edge chunk: LDS histogram, ONE returning
// global atomic per (block,bucket) to reserve a range, then place records at
// base + LDS-local cursor -> contiguous ~10-record runs per bucket.
__global__ void scatter_kernel(const int* __restrict__ src, const int* __restrict__ dst,
                               int E, int* __restrict__ bucketCur, uint2* __restrict__ rec) {
    __shared__ int hist[1024];
    __shared__ int base[1024];
    int t = threadIdx.x;
    int e0 = blockIdx.x * SCHUNK;
    int e1 = MIN(E, e0 + SCHUNK);
    for (int i = t; i < 1024; i += 256) hist[i] = 0;
    __syncthreads();
    for (int e = e0 + t; e < e1; e += 256)
        atomicAdd(&hist[dst[e] >> BUCKET_SHIFT], 1);
    __syncthreads();
    for (int i = t; i < 1024; i += 256) {
        int c = hist[i];
        base[i] = c ? atomicAdd(&bucketCur[i], c) : 0;   // ~98 per address total
        hist[i] = 0;                                      // reuse as local cursor
    }
    __syncthreads();
    for (int e = e0 + t; e < e1; e += 256) {
        int d = dst[e];
        int b = d >> BUCKET_SHIFT;
        int pos = base[b] + atomicAdd(&hist[b], 1);       // LDS atomic, cheap
        rec[pos] = make_uint2((unsigned)src[e], (unsigned)d);
    }
}

// Pass C: one block per bucket — per-node degree, local scan, rowptr/dinv/csr fill
__global__ void bucket_build(const uint2* __restrict__ rec, const int* __restrict__ bucketBase,
                             int* __restrict__ rowptr, int* __restrict__ csr_src,
                             float* __restrict__ dinv, int N, int E) {
    __shared__ int lcnt[256];   // only [0,64) used; padded for uniform scan
    __shared__ int sm[256];
    __shared__ int lcur[64];
    int b = blockIdx.x;
    int t = threadIdx.x;
    int beg = bucketBase[b], end = bucketBase[b + 1];
    lcnt[t] = 0;
    __syncthreads();
    for (int i = beg + t; i < end; i += 256)
        atomicAdd(&lcnt[rec[i].y & (BUCKET_SIZE - 1)], 1);
    __syncthreads();
    int v = lcnt[t];
    sm[t] = v;
    __syncthreads();
    for (int off = 1; off < 256; off <<= 1) {
        int add = (t >= off) ? sm[t - off] : 0;
        __syncthreads();
        sm[t] += add;
        __syncthreads();
    }
    int excl = sm[t] - v;
    if (t < BUCKET_SIZE) {
        int node = b * BUCKET_SIZE + t;
        if (node < N) {
            rowptr[node] = beg + excl;
            dinv[node] = rsqrtf((float)(v + 1));   // self loop -> deg >= 1
        }
        lcur[t] = beg + excl;
    }
    __syncthreads();
    for (int i = beg + t; i < end; i += 256) {
        uint2 r = rec[i];
        int pos = atomicAdd(&lcur[r.y & (BUCKET_SIZE - 1)], 1);
        csr_src[pos] = (int)r.x;
    }
    if (b == 0 && t == 0) rowptr[N] = E;
}

// ---------------------------------------------------------------------------
// Weight fp32 -> f16 conversion (once per call; 3 arrays in one launch)
// ---------------------------------------------------------------------------

__global__ void cvt_weights(const float* __restrict__ a, _Float16* __restrict__ oa, int na,
                            const float* __restrict__ b, _Float16* __restrict__ ob, int nb,
                            const float* __restrict__ c, _Float16* __restrict__ oc, int nc) {
    int i = blockIdx.x * blockDim.x + threadIdx.x;
    if (i < na) oa[i] = (_Float16)a[i];
    if (i < nb) ob[i] = (_Float16)b[i];
    if (i < nc) oc[i] = (_Float16)c[i];
}

// ---------------------------------------------------------------------------
// Aggregation over f16 H: X[node] = relu( di*( di*H[node] + sum dinv[s]*H[s] ) )
// 1 wave per node, 1 dword (2 f16 ch) per lane; 64-edge batches via shfl,
// 8 independent row gathers in flight. Accumulate fp32; X written f16.
// ---------------------------------------------------------------------------

__global__ void agg_kernel(const half2_t* __restrict__ Hb, const float* __restrict__ dinv,
                           const int* __restrict__ rowptr, const int* __restrict__ csr_src,
                           half2_t* __restrict__ X, int N) {
    int node = blockIdx.x * 4 + (threadIdx.x >> 6);
    int t = threadIdx.x & 63;
    if (node >= N) return;
    float di = dinv[node];
    half2_t hu = Hb[(size_t)node * 64 + t];
    float2 acc;
    acc.x = (float)hu.x * di;
    acc.y = (float)hu.y * di;
    int beg = rowptr[node];
    int end = rowptr[node + 1];

    for (int base = beg; base < end; base += 64) {
        int idx = base + t;
        bool valid = idx < end;
        int s_lane = valid ? csr_src[idx] : node;    // safe address for pads
        float w_lane = valid ? dinv[s_lane] : 0.0f;  // zero weight for pads
        int m = end - base;
        if (m > 64) m = 64;
        int mm = (m + 7) & ~7;                       // pads contribute 0
        for (int j = 0; j < mm; j += 8) {
            int s0 = __shfl(s_lane, j + 0), s1 = __shfl(s_lane, j + 1);
            int s2 = __shfl(s_lane, j + 2), s3 = __shfl(s_lane, j + 3);
            int s4 = __shfl(s_lane, j + 4), s5 = __shfl(s_lane, j + 5);
            int s6 = __shfl(s_lane, j + 6), s7 = __shfl(s_lane, j + 7);
            float w0 = __shfl(w_lane, j + 0), w1 = __shfl(w_lane, j + 1);
            float w2 = __shfl(w_lane, j + 2), w3 = __shfl(w_lane, j + 3);
            float w4 = __shfl(w_lane, j + 4), w5 = __shfl(w_lane, j + 5);
            float w6 = __shfl(w_lane, j + 6), w7 = __shfl(w_lane, j + 7);
            half2_t u0 = Hb[(size_t)s0 * 64 + t];
            half2_t u1 = Hb[(size_t)s1 * 64 + t];
            half2_t u2 = Hb[(size_t)s2 * 64 + t];
            half2_t u3 = Hb[(size_t)s3 * 64 + t];
            half2_t u4 = Hb[(size_t)s4 * 64 + t];
            half2_t u5 = Hb[(size_t)s5 * 64 + t];
            half2_t u6 = Hb[(size_t)s6 * 64 + t];
            half2_t u7 = Hb[(size_t)s7 * 64 + t];
            acc.x = fmaf((float)u0.x, w0, acc.x); acc.y = fmaf((float)u0.y, w0, acc.y);
            acc.x = fmaf((float)u1.x, w1, acc.x); acc.y = fmaf((float)u1.y, w1, acc.y);
            acc.x = fmaf((float)u2.x, w2, acc.x); acc.y = fmaf((float)u2.y, w2, acc.y);
            acc.x = fmaf((float)u3.x, w3, acc.x); acc.y = fmaf((float)u3.y, w3, acc.y);
            acc.x = fmaf((float)u4.x, w4, acc.x); acc.y = fmaf((float)u4.y, w4, acc.y);
            acc.x = fmaf((float)u5.x, w5, acc.x); acc.y = fmaf((float)u5.y, w5, acc.y);
            acc.x = fmaf((float)u6.x, w6, acc.x); acc.y = fmaf((float)u6.y, w6, acc.y);
            acc.x = fmaf((float)u7.x, w7, acc.x); acc.y = fmaf((float)u7.y, w7, acc.y);
        }
    }
    half2_t o;
    o.x = (_Float16)fmaxf(acc.x * di, 0.0f);
    o.y = (_Float16)fmaxf(acc.y * di, 0.0f);
    X[(size_t)node * 64 + t] = o;
}

// ---------------------------------------------------------------------------
// MFMA f16 GEMM, K=128 fixed, BM=64, 256 threads (4 waves, 16 rows/wave).
// ---------------------------------------------------------------------------

template <int BN, bool A_F16, bool RELU, bool BIAS, bool ACCUM, bool F16OUT>
__global__ __launch_bounds__(256)
void mfma_gemm(const void* __restrict__ Av,
               const _Float16* __restrict__ W, int ldw,
               const float* __restrict__ bias,
               void* __restrict__ Cv, int ldc, int M) {
    constexpr int NT = BN / 16;
    __shared__ __align__(16) _Float16 As[64][136];
    __shared__ __align__(16) _Float16 Ws[BN][136];

    int tid = threadIdx.x;
    int rowBase = blockIdx.x * 64;

#pragma unroll
    for (int i = tid; i < BN * 16; i += 256) {
        int n = i >> 4, k8 = (i & 15) * 8;
        uint4 v = *(const uint4*)(W + (size_t)n * ldw + k8);
        *(uint4*)(&Ws[n][k8]) = v;
    }
    if (A_F16) {
        const _Float16* A = (const _Float16*)Av;
#pragma unroll
        for (int i = tid; i < 64 * 16; i += 256) {
            int r = i >> 4, k8 = (i & 15) * 8;
            int gr = rowBase + r;
            uint4 v = make_uint4(0, 0, 0, 0);
            if (gr < M) v = *(const uint4*)(A + (size_t)gr * 128 + k8);
            *(uint4*)(&As[r][k8]) = v;
        }
    } else {
        const float* A = (const float*)Av;
#pragma unroll
        for (int i = tid; i < 64 * 32; i += 256) {
            int r = i >> 5, c4 = (i & 31) * 4;
            int gr = rowBase + r;
            half4_t h = {0, 0, 0, 0};
            if (gr < M) {
                float4 v = *(const float4*)(A + (size_t)gr * 128 + c4);
                h.x = (_Float16)v.x; h.y = (_Float16)v.y;
                h.z = (_Float16)v.z; h.w = (_Float16)v.w;
            }
            *(half4_t*)(&As[r][c4]) = h;
        }
    }
    __syncthreads();

    int w = tid >> 6;
    int lane = tid & 63;
    int lrow = lane & 15;
    int kq = (lane >> 4) * 8;

    floatx4 acc[NT];
#pragma unroll
    for (int nt = 0; nt < NT; ++nt) acc[nt] = (floatx4){0.f, 0.f, 0.f, 0.f};

#pragma unroll
    for (int ks = 0; ks < 4; ++ks) {
        int kk = ks * 32 + kq;
        half8_t a = *(const half8_t*)(&As[w * 16 + lrow][kk]);
#pragma unroll
        for (int nt = 0; nt < NT; ++nt) {
            half8_t b = *(const half8_t*)(&Ws[nt * 16 + lrow][kk]);
            acc[nt] = __builtin_amdgcn_mfma_f32_16x16x32_f16(a, b, acc[nt], 0, 0, 0);
        }
    }

    int quad = lane >> 4;
#pragma unroll
    for (int nt = 0; nt < NT; ++nt) {
        int col = nt * 16 + lrow;
        float bv = BIAS ? bias[col] : 0.0f;
#pragma unroll
        for (int reg = 0; reg < 4; ++reg) {
            int gr = rowBase + w * 16 + quad * 4 + reg;
            if (gr < M) {
                float v = acc[nt][reg] + bv;
                if (RELU) v = fmaxf(v, 0.0f);
                if (F16OUT) {
                    _Float16* C = (_Float16*)Cv;
                    C[(size_t)gr * ldc + col] = (_Float16)v;
                } else {
                    float* C = (float*)Cv;
                    if (ACCUM) v += C[(size_t)gr * ldc + col];
                    C[(size_t)gr * ldc + col] = v;
                }
            }
        }
    }
}

// ---------------------------------------------------------------------------
// launch
// ---------------------------------------------------------------------------

extern "C" void kernel_launch(void* const* d_in, const int* in_sizes, int n_in,
                              void* d_out, int out_size, void* d_ws, size_t ws_size,
                              hipStream_t stream) {
    const float* x     = (const float*)d_in[0];
    const int*   ei    = (const int*)d_in[1];
    const float* W_in  = (const float*)d_in[2];
    const float* b_in  = (const float*)d_in[3];
    const float* Wc    = (const float*)d_in[4];
    const float* bc    = (const float*)d_in[5];
    const float* W_out = (const float*)d_in[6];
    const float* b_out = (const float*)d_in[7];
    float* out = (float*)d_out;

    const int HID = 128;
    const int N = in_sizes[0] / HID;   // 50000
    const int E = in_sizes[1] / 2;     // 800000
    const int L = 4;
    const int* src = ei;
    const int* dst = ei + E;
    const int NB = (N + BUCKET_SIZE - 1) >> BUCKET_SHIFT;   // 782

    char* ws = (char*)d_ws;
    size_t off = 0;
    auto carve = [&](size_t bytes) {
        void* p = ws + off;
        off += (bytes + 255) & ~(size_t)255;
        return p;
    };
    float* dinv      = (float*)carve((size_t)N * 4);
    int*   rowptr    = (int*)carve((size_t)(N + 1) * 4);
    int*   csr_src   = (int*)carve((size_t)E * 4);
    uint2* rec       = (uint2*)carve((size_t)E * 8);
    int*   bucketCnt = (int*)carve((size_t)1024 * 4);
    int*   bucketBase= (int*)carve((size_t)1025 * 4);
    int*   bucketCur = (int*)carve((size_t)1024 * 4);
    _Float16* bufA   = (_Float16*)carve((size_t)N * HID * 2);
    _Float16* bufH   = (_Float16*)carve((size_t)N * HID * 2);
    _Float16* Wf_in  = (_Float16*)carve((size_t)HID * HID * 2);
    _Float16* Wf_c   = (_Float16*)carve((size_t)L * HID * HID * 2);
    _Float16* Wf_out = (_Float16*)carve((size_t)64 * 512 * 2);
    (void)ws_size;

    // ---- bucketed CSR + norm build ----
    hipMemsetAsync(bucketCnt, 0, (size_t)1024 * 4, stream);
    hist_kernel<<<512, 256, 0, stream>>>(dst, E, bucketCnt, NB);
    bucket_scan<<<1, 1024, 0, stream>>>(bucketCnt, bucketBase, bucketCur, NB, E);
    scatter_kernel<<<(E + SCHUNK - 1) / SCHUNK, 256, 0, stream>>>(src, dst, E, bucketCur, rec);
    bucket_build<<<NB, 256, 0, stream>>>(rec, bucketBase, rowptr, csr_src, dinv, N, E);

    // ---- weights -> f16 ----
    cvt_weights<<<(L * HID * HID + 255) / 256, 256, 0, stream>>>(
        W_in, Wf_in, HID * HID,
        Wc, Wf_c, L * HID * HID,
        W_out, Wf_out, 64 * 512);

    int gemm_blocks = (N + 63) / 64;

    // ---- input projection: bufA = f16( relu(x @ W_in^T + b_in) ) ----
    mfma_gemm<128, false, true, true, false, true>
        <<<gemm_blocks, 256, 0, stream>>>(x, Wf_in, HID, b_in, bufA, HID, N);

    // ---- conv layers ----
    for (int l = 0; l < L; ++l) {
        mfma_gemm<128, true, false, true, false, true>
            <<<gemm_blocks, 256, 0, stream>>>(bufA, Wf_c + (size_t)l * HID * HID, HID,
                                              bc + (size_t)l * HID, bufH, HID, N);
        agg_kernel<<<(N + 3) / 4, 256, 0, stream>>>((const half2_t*)bufH, dinv, rowptr,
                                                    csr_src, (half2_t*)bufA, N);
        if (l == 0) {
            mfma_gemm<64, true, false, true, false, false>
                <<<gemm_blocks, 256, 0, stream>>>(bufA, Wf_out + (size_t)l * HID, 512,
                                                  b_out, out, 64, N);
        } else {
            mfma_gemm<64, true, false, false, true, false>
                <<<gemm_blocks, 256, 0, stream>>>(bufA, Wf_out + (size_t)l * HID, 512,
                                                  nullptr, out, 64, N);
        }
    }
}